// Round 8
// baseline (141.061 us; speedup 1.0000x reference)
//
#include <hip/hip_runtime.h>
#include <math.h>

#define NB 16
#define NC 256
#define NHW 1024
#define NE 512
#define NDQ 4
#define NLQ 4
#define NQB 6
#define QDIM 64
#define PIX 8      // pixels per k_main block
#define XPAD 260   // xs row stride (floats)
#define MSP 12     // ms row stride

typedef float v2f __attribute__((ext_vector_type(2)));

// ======== constexpr circuit algebra (CNOT ring is GF(2)-linear) ========
// forward ring map f: value transform of the reference's CNOT cascade
constexpr int fwd1(int i) {
    int r = i;
    for (int c = 0; c < NQB; ++c) {
        int t = (c + 1) % NQB;
        if ((r >> (NQB - 1 - c)) & 1) r ^= 1 << (NQB - 1 - t);
    }
    return r;
}
constexpr int fwdl(int s, int l) { for (int i = 0; i < l; ++i) s = fwd1(s); return s; }
constexpr int parity6(int x) { x ^= x >> 4; x ^= x >> 2; x ^= x >> 1; return x & 1; }

// Lazy-permutation tables: gate (l,q) on logical mask m acts on STORAGE pairs
// (s, s^M) with M = f^{-l}(m); element s is "lo" iff parity(s & V)==0 where
// bit t of V = bit(5-q) of f^l(2^t). Measurement sign for data qubit d:
// parity(s & W[d]), W bit t = bit(5-d) of f^4(2^t). No physical perm ever.
struct GateTab { int M[NLQ][NQB]; int V[NLQ][NQB]; int W[NDQ]; };
constexpr GateTab make_tab() {
    GateTab g{};
    for (int l = 0; l < NLQ; ++l)
        for (int q = 0; q < NQB; ++q) {
            int m = 1 << (NQB - 1 - q);
            for (int x = 0; x < QDIM; ++x) if (fwdl(x, l) == m) { g.M[l][q] = x; break; }
            int V = 0;
            for (int t = 0; t < NQB; ++t) V |= ((fwdl(1 << t, l) >> (NQB - 1 - q)) & 1) << t;
            g.V[l][q] = V;
        }
    for (int d = 0; d < NDQ; ++d) {
        int W = 0;
        for (int t = 0; t < NQB; ++t) W |= ((fwdl(1 << t, NLQ) >> (NQB - 1 - d)) & 1) << t;
        g.W[d] = W;
    }
    return g;
}
constexpr GateTab GT = make_tab();

// ---- Kernel 1: fused GroupNorm stats (blk<512) + style matvec (blk>=512) ----
__global__ __launch_bounds__(256) void k_pre(const float* __restrict__ x,
                                             const float* __restrict__ emb,
                                             const float* __restrict__ w_style,
                                             const float* __restrict__ b_style,
                                             const float* __restrict__ theta,
                                             float* __restrict__ mu,
                                             float* __restrict__ rs,
                                             float* __restrict__ A) {
    if (blockIdx.x < 512) {
        int bg = blockIdx.x;
        const float4* xp = (const float4*)(x + (size_t)bg * 8 * NHW);
        float s = 0.f, ss = 0.f;
        for (int i = threadIdx.x; i < 8 * NHW / 4; i += 256) {
            float4 v = xp[i];
            s  += v.x + v.y + v.z + v.w;
            ss += v.x*v.x + v.y*v.y + v.z*v.z + v.w*v.w;
        }
        __shared__ float red0[4], red1[4];
        #pragma unroll
        for (int o = 32; o; o >>= 1) { s += __shfl_down(s, o); ss += __shfl_down(ss, o); }
        int lane = threadIdx.x & 63, w = threadIdx.x >> 6;
        if (lane == 0) { red0[w] = s; red1[w] = ss; }
        __syncthreads();
        if (threadIdx.x == 0) {
            s  = red0[0] + red0[1] + red0[2] + red0[3];
            ss = red1[0] + red1[1] + red1[2] + red1[3];
            float m = s * (1.f / 8192.f);
            float var = ss * (1.f / 8192.f) - m * m;
            mu[bg] = m;
            rs[bg] = rsqrtf(var + 1e-5f);
        }
    } else {
        int b = blockIdx.x - 512;
        __shared__ float es[NE];
        int t = threadIdx.x;
        for (int i = t; i < NE; i += 256) {
            float v = emb[b * NE + i];
            es[i] = v / (1.f + __expf(-v));
        }
        __syncthreads();
        int j0 = t >> 3, sub = t & 7;
        for (int pass = 0; pass < 6; ++pass) {
            int j = pass * 32 + j0;
            const float* wr = w_style + (size_t)j * NE + sub * 64;
            const float* er = es + sub * 64;
            float acc = 0.f;
            #pragma unroll
            for (int i = 0; i < 64; i += 4) {
                float4 w4 = *(const float4*)(wr + i);
                acc = fmaf(w4.x, er[i],   acc);
                acc = fmaf(w4.y, er[i+1], acc);
                acc = fmaf(w4.z, er[i+2], acc);
                acc = fmaf(w4.w, er[i+3], acc);
            }
            acc += __shfl_xor(acc, 1);
            acc += __shfl_xor(acc, 2);
            acc += __shfl_xor(acc, 4);
            if (sub == 0) A[b * 192 + j] = theta[j] + b_style[j] + acc;
        }
    }
}

// ---- Kernel 2: fused main. grid = 2048 x 128 thr, PIX=8, 2 THREADS/CIRCUIT ----
// (128,2): VGPR cap 256 — do NOT tighten (R6: (128,4) forced 64 VGPR + spill).
__global__ __launch_bounds__(128, 2) void k_main(
    const float* __restrict__ x,
    const float* __restrict__ gamma,
    const float* __restrict__ beta,
    const float* __restrict__ w_in,
    const float* __restrict__ b_in,
    const float* __restrict__ A,
    const float* __restrict__ w_out,
    const float* __restrict__ b_out,
    const float* __restrict__ mu,
    const float* __restrict__ rs,
    float* __restrict__ out) {

    __shared__ float xs[PIX * XPAD];   // [p][c]: normalized h, later raw-x stash; 8.3 KB
    __shared__ float as_[PIX * 36];    // ang [p][o], 1.2 KB
    __shared__ float ms[32 * MSP];     // meas [o][p], 1.5 KB

    int blk = blockIdx.x;
    int b = blk >> 7;
    int pbase = (blk & 127) * PIX;
    int t = threadIdx.x;
    int c0 = t >> 1, f4 = (t & 1) * 4;   // P0/P1: 4 channels (c0+64k) x 4 pixels

    // ---- P0: load x tile to registers (the only x read in this kernel) ----
    float4 xr[4];
    #pragma unroll
    for (int k = 0; k < 4; ++k) {
        int c = c0 + 64 * k;
        xr[k] = *(const float4*)(x + (size_t)(b * NC + c) * NHW + pbase + f4);
    }

    // ---- P1: normalize -> xs [p][c] ----
    #pragma unroll
    for (int k = 0; k < 4; ++k) {
        int c = c0 + 64 * k;
        int g = b * 32 + (c >> 3);
        float sc = rs[g] * gamma[c];
        float sh = fmaf(-mu[g], sc, beta[c]);
        float4 v = xr[k];
        xs[(f4 + 0) * XPAD + c] = fmaf(v.x, sc, sh);
        xs[(f4 + 1) * XPAD + c] = fmaf(v.y, sc, sh);
        xs[(f4 + 2) * XPAD + c] = fmaf(v.z, sc, sh);
        xs[(f4 + 3) * XPAD + c] = fmaf(v.w, sc, sh);
    }
    __syncthreads();

    // ---- P2: ang[p][o]; thread = (2 outputs, 1 pixel), v2f-packed channels ----
    {
        int og = t >> 3, p = t & 7;
        int o0 = og * 2;
        const v2f* h2  = (const v2f*)(xs + p * XPAD);
        const v2f* w02 = (const v2f*)(w_in + o0 * NC);
        const v2f* w12 = (const v2f*)(w_in + (o0 + 1) * NC);
        v2f a0 = {0.f, 0.f}, a1 = {0.f, 0.f};
        #pragma unroll 16
        for (int c2 = 0; c2 < NC / 2; ++c2) {
            v2f h = h2[c2];
            a0 = __builtin_elementwise_fma(w02[c2], h, a0);
            a1 = __builtin_elementwise_fma(w12[c2], h, a1);
        }
        as_[p * 36 + o0]     = a0.x + a0.y + b_in[o0];
        as_[p * 36 + o0 + 1] = a1.x + a1.y + b_in[o0 + 1];
    }
    __syncthreads();

    // ---- stash raw x into xs (P2 consumed the normalized copy) ----
    #pragma unroll
    for (int k = 0; k < 4; ++k) {
        int c = c0 + 64 * k;
        float4 v = xr[k];
        xs[(f4 + 0) * XPAD + c] = v.x;
        xs[(f4 + 1) * XPAD + c] = v.y;
        xs[(f4 + 2) * XPAD + c] = v.z;
        xs[(f4 + 3) * XPAD + c] = v.w;
    }

    // ---- P3: circuits, 2 threads per circuit (sub = t&1 owns bit5 = sub half) ----
    {
        int cir = t >> 1, sub = t & 1;
        int g = cir >> 3, p = cir & 7;
        float4 angv = *(const float4*)(as_ + p * 36 + g * 4);
        float angp[NDQ] = {angv.x, angv.y, angv.z, angv.w};
        float Ar[24];
        {
            const float4* Ab4 = (const float4*)(A + b * 192 + g * 24);
            #pragma unroll
            for (int j = 0; j < 6; ++j) {
                float4 a4 = Ab4[j];
                Ar[4*j] = a4.x; Ar[4*j+1] = a4.y; Ar[4*j+2] = a4.z; Ar[4*j+3] = a4.w;
            }
        }

        // my 32 storage elements: global index = sub*32 + (2k, 2k+1)
        v2f st2[16];
        #pragma unroll
        for (int k = 0; k < 16; ++k) st2[k] = (v2f){0.f, 0.f};
        if (sub == 0) st2[0].x = 1.f;

        #pragma unroll
        for (int l = 0; l < NLQ; ++l) {
            #pragma unroll
            for (int q = 0; q < NQB; ++q) {
                const int M  = GT.M[l][q];   // storage-space pair mask
                const int V  = GT.V[l][q];   // lo-parity vector
                const int ML = M & 31;
                const int KD = ML >> 1;
                float a = Ar[l * NQB + q] + (q < NDQ ? angp[q] : 0.f);
                float sn, cs;
                __sincosf(0.5f * a, &sn, &cs);
                // element s: new = cs*mine[s] + sgn(s)*sn*old[s^M],
                // sgn(s) = parity(s&V) ? + : -.  s = sub*32+j ->
                // parity = parity(j & V31) ^ (sub & bit5(V)).
                float snS = (V & 32) ? (sub ? -sn : sn) : sn;
                v2f cs2 = {cs, cs};
                if (M & 32) {
                    // cross-thread pairing: fetch partner half
                    v2f pstl[16];
                    #pragma unroll
                    for (int k = 0; k < 16; ++k) {
                        pstl[k].x = __shfl_xor(st2[k].x, 1);
                        pstl[k].y = __shfl_xor(st2[k].y, 1);
                    }
                    #pragma unroll
                    for (int k = 0; k < 16; ++k) {
                        v2f ov = pstl[k ^ KD];
                        if (M & 1) ov = __builtin_shufflevector(ov, ov, 1, 0);
                        v2f co = { parity6((2*k)     & (V & 31)) ? snS : -snS,
                                   parity6((2*k + 1) & (V & 31)) ? snS : -snS };
                        st2[k] = __builtin_elementwise_fma(co, ov, cs2 * st2[k]);
                    }
                } else {
                    v2f nst[16];
                    #pragma unroll
                    for (int k = 0; k < 16; ++k) {
                        v2f ov = st2[k ^ KD];
                        if (M & 1) ov = __builtin_shufflevector(ov, ov, 1, 0);
                        v2f co = { parity6((2*k)     & (V & 31)) ? snS : -snS,
                                   parity6((2*k + 1) & (V & 31)) ? snS : -snS };
                        nst[k] = __builtin_elementwise_fma(co, ov, cs2 * st2[k]);
                    }
                    #pragma unroll
                    for (int k = 0; k < 16; ++k) st2[k] = nst[k];
                }
            }
            // NO physical permutation: folded into M/V/W tables
        }

        // probs in place
        #pragma unroll
        for (int k = 0; k < 16; ++k) st2[k] = st2[k] * st2[k];
        // measurement: sign_d(s) = parity(s & W[d]) ? -1 : +1 (ZSIGN +1 at bit==0)
        #pragma unroll
        for (int d = 0; d < NDQ; ++d) {
            const int W = GT.W[d];
            v2f acc2 = {0.f, 0.f};
            #pragma unroll
            for (int k = 0; k < 16; ++k) {
                v2f sg = { parity6((2*k)     & (W & 31)) ? -1.f : 1.f,
                           parity6((2*k + 1) & (W & 31)) ? -1.f : 1.f };
                acc2 = __builtin_elementwise_fma(sg, st2[k], acc2);
            }
            float pd = acc2.x + acc2.y;
            if (W & 32) pd = sub ? -pd : pd;
            pd += __shfl_xor(pd, 1);
            if (sub == 0) ms[(g * 4 + d) * MSP + p] = pd;
        }
    }
    __syncthreads();

    // ---- P4: out = w_out.meas + b_out + x; thread = (8 ch x 2 pixels), pk-packed ----
    {
        int cb = t >> 2, f2 = (t & 3) * 2;
        v2f mreg[32];
        #pragma unroll
        for (int o = 0; o < 32; ++o)
            mreg[o] = *(const v2f*)(ms + o * MSP + f2);
        #pragma unroll
        for (int k = 0; k < 8; ++k) {
            int c = cb + 32 * k;
            const float* wr = w_out + c * 32;
            v2f acc = {0.f, 0.f};
            #pragma unroll
            for (int o4 = 0; o4 < 8; ++o4) {
                float4 w4 = *(const float4*)(wr + o4 * 4);
                acc = __builtin_elementwise_fma((v2f){w4.x, w4.x}, mreg[4*o4],     acc);
                acc = __builtin_elementwise_fma((v2f){w4.y, w4.y}, mreg[4*o4 + 1], acc);
                acc = __builtin_elementwise_fma((v2f){w4.z, w4.z}, mreg[4*o4 + 2], acc);
                acc = __builtin_elementwise_fma((v2f){w4.w, w4.w}, mreg[4*o4 + 3], acc);
            }
            float bo = b_out[c];
            float x0 = xs[(f2 + 0) * XPAD + c];
            float x1 = xs[(f2 + 1) * XPAD + c];
            float2 r = {acc.x + bo + x0, acc.y + bo + x1};
            *(float2*)(out + (size_t)(b * NC + c) * NHW + pbase + f2) = r;
        }
    }
}

extern "C" void kernel_launch(void* const* d_in, const int* in_sizes, int n_in,
                              void* d_out, int out_size, void* d_ws, size_t ws_size,
                              hipStream_t stream) {
    const float* x       = (const float*)d_in[0];
    const float* emb     = (const float*)d_in[1];
    const float* gamma   = (const float*)d_in[2];
    const float* beta    = (const float*)d_in[3];
    const float* w_in    = (const float*)d_in[4];
    const float* b_in    = (const float*)d_in[5];
    const float* theta   = (const float*)d_in[6];
    const float* w_style = (const float*)d_in[7];
    const float* b_style = (const float*)d_in[8];
    const float* w_out   = (const float*)d_in[9];
    const float* b_out   = (const float*)d_in[10];
    float* out = (float*)d_out;

    float* ws = (float*)d_ws;
    float* mu = ws;           // 512
    float* rs = ws + 512;     // 512
    float* A  = ws + 1024;    // 3072

    k_pre<<<512 + NB, 256, 0, stream>>>(x, emb, w_style, b_style, theta, mu, rs, A);
    k_main<<<NB * 128, 128, 0, stream>>>(x, gamma, beta, w_in, b_in, A,
                                         w_out, b_out, mu, rs, out);
}